// Round 5
// baseline (35.837 us; speedup 1.0000x reference)
//
#include <hip/hip_runtime.h>

#define HW 16384      // 128*128
#define NCH 128       // channels
#define CCH 4         // channels per thread
#define LANG 256
#define NH 128
#define NOP 6

typedef float f4 __attribute__((ext_vector_type(4)));

// Per-batch coefficients in d_ws: coefs[b*12 + 0..5] = gamma[b,k]*wr[k],
// coefs[b*12 + 6..11] = beta[b,k]*wr[k]; coefs[48] = sum(wr); coefs[49] = br.
__global__ __launch_bounds__(256) void coef_kernel(
    const float* __restrict__ lang, const float* __restrict__ Ws,
    const float* __restrict__ bs, const float* __restrict__ Wg,
    const float* __restrict__ bg, const float* __restrict__ Wb,
    const float* __restrict__ bb, const float* __restrict__ Wr,
    const float* __restrict__ br, float* __restrict__ coefs) {
  const int b = blockIdx.x;
  const int tid = threadIdx.x;
  const int wave = tid >> 6, lane = tid & 63;
  __shared__ float actv[NH];

  const f4 lv = *(const f4*)(lang + b * LANG + lane * 4);

  #pragma unroll 8
  for (int m = 0; m < 32; ++m) {
    const int j = wave * 32 + m;
    const f4 wv = *(const f4*)(Ws + (size_t)j * LANG + lane * 4);
    float p = lv.x * wv.x + lv.y * wv.y + lv.z * wv.z + lv.w * wv.w;
    #pragma unroll
    for (int off = 32; off; off >>= 1) p += __shfl_xor(p, off);
    if (lane == 0) actv[j] = p + bs[j];
  }
  __syncthreads();

  const float a0 = actv[lane * 2], a1 = actv[lane * 2 + 1];
  #pragma unroll
  for (int r = 0; r < 3; ++r) {
    const int k = wave + 4 * r;              // 0..11
    const int kk = (k < NOP) ? k : k - NOP;  // row in Wg/Wb
    const float* W = ((k < NOP) ? Wg : Wb) + kk * NH;
    float p = a0 * W[lane * 2] + a1 * W[lane * 2 + 1];
    #pragma unroll
    for (int off = 32; off; off >>= 1) p += __shfl_xor(p, off);
    if (lane == 0) {
      const float bias = (k < NOP) ? bg[kk] : bb[kk];
      coefs[b * 12 + k] = (p + bias) * Wr[kk];
    }
  }
  if (b == 0 && tid == 0) {
    float s = 0.f;
    #pragma unroll
    for (int k = 0; k < NOP; ++k) s += Wr[k];
    coefs[48] = s;
    coefs[49] = br[0];
  }
}

// Streaming affine: out[b,c,p] = x[b,c,p] * scale[b,p] + shift[b,p].
// 2048 blocks (8/CU, 100% occupancy). All 10 loads per thread issued
// into registers before any compute/store to maximize loads in flight.
__global__ __launch_bounds__(256) void apply_kernel(
    const float* __restrict__ x, const float* __restrict__ sem,
    const float* __restrict__ coefs, float* __restrict__ out) {
  const int b = blockIdx.z;
  const int cbase = blockIdx.y * CCH;
  const int pix = (blockIdx.x * 256 + threadIdx.x) * 4;

  const size_t base = ((size_t)b * NCH + cbase) * HW + pix;
  const float* xb = x + base;
  const float* semb = sem + ((size_t)b * 8 + 2) * HW + pix;

  // ---- issue all loads (independent) ----
  f4 xa[CCH];
  #pragma unroll
  for (int c = 0; c < CCH; ++c) xa[c] = *(const f4*)(xb + (size_t)c * HW);
  f4 sv[NOP];
  #pragma unroll
  for (int k = 0; k < NOP; ++k) sv[k] = *(const f4*)(semb + (size_t)k * HW);

  // coefs are wave-uniform -> scalar loads
  const float* gk = coefs + b * 12;
  const float wrsum = coefs[48];
  const float brv = coefs[49];

  f4 scale = {wrsum, wrsum, wrsum, wrsum};
  f4 shift = {brv, brv, brv, brv};
  #pragma unroll
  for (int k = 0; k < NOP; ++k) {
    scale += gk[k] * sv[k];
    shift += gk[NOP + k] * sv[k];
  }

  float* ob = out + base;
  #pragma unroll
  for (int c = 0; c < CCH; ++c)
    *(f4*)(ob + (size_t)c * HW) = xa[c] * scale + shift;
}

extern "C" void kernel_launch(void* const* d_in, const int* in_sizes, int n_in,
                              void* d_out, int out_size, void* d_ws, size_t ws_size,
                              hipStream_t stream) {
  const float* x    = (const float*)d_in[0];
  const float* lang = (const float*)d_in[1];
  const float* sem  = (const float*)d_in[2];
  const float* Ws   = (const float*)d_in[3];
  const float* bs   = (const float*)d_in[4];
  const float* Wg   = (const float*)d_in[5];
  const float* bg   = (const float*)d_in[6];
  const float* Wb   = (const float*)d_in[7];
  const float* bb   = (const float*)d_in[8];
  const float* Wr   = (const float*)d_in[9];
  const float* br   = (const float*)d_in[10];
  float* out = (float*)d_out;
  float* coefs = (float*)d_ws;  // 50 floats

  coef_kernel<<<dim3(4), dim3(256), 0, stream>>>(lang, Ws, bs, Wg, bg, Wb, bb,
                                                 Wr, br, coefs);

  dim3 grid(HW / (256 * 4), NCH / CCH, 4);  // (16, 32, 4) = 2048 blocks
  apply_kernel<<<grid, dim3(256), 0, stream>>>(x, sem, coefs, out);
}

// Round 6
// 32.921 us; speedup vs baseline: 1.0886x; 1.0886x over previous
//
#include <hip/hip_runtime.h>

#define HW 16384      // 128*128
#define NCH 128       // channels
#define CCH 8         // channels per thread
#define LANG 256
#define NH 128
#define NOP 6

typedef float f4 __attribute__((ext_vector_type(4)));

// Single fused kernel, 1024 blocks x 256 threads.
// Per block: issue lang + 8 x-tiles + 6 sem-tiles into registers up front
// (latency hides under the coef GEMV, whose Ws reads are L2/LLC-hot),
// compute the 12 per-batch coefficients wave-parallel, combine, store.
__global__ __launch_bounds__(256) void fused_kernel(
    const float* __restrict__ x, const float* __restrict__ lang,
    const float* __restrict__ sem,
    const float* __restrict__ Ws, const float* __restrict__ bs,
    const float* __restrict__ Wg, const float* __restrict__ bg,
    const float* __restrict__ Wb, const float* __restrict__ bb,
    const float* __restrict__ Wr, const float* __restrict__ br,
    float* __restrict__ out) {
  const int b = blockIdx.z;
  const int cbase = blockIdx.y * CCH;
  const int tid = threadIdx.x;
  const int wave = tid >> 6, lane = tid & 63;
  const int pix = (blockIdx.x * 256 + tid) * 4;

  __shared__ float actv[NH];
  __shared__ float cf[12];  // 0..5: gamma*wr, 6..11: beta*wr

  // ---- issue lang first (needed soonest by the prologue) ----
  const f4 lv = *(const f4*)(lang + b * LANG + lane * 4);

  // ---- issue all streaming loads up front (consumed last) ----
  const size_t base = ((size_t)b * NCH + cbase) * HW + pix;
  const float* xb = x + base;
  const float* semb = sem + ((size_t)b * 8 + 2) * HW + pix;
  f4 xa[CCH];
  #pragma unroll
  for (int c = 0; c < CCH; ++c) xa[c] = *(const f4*)(xb + (size_t)c * HW);
  f4 sv[NOP];
  #pragma unroll
  for (int k = 0; k < NOP; ++k) sv[k] = *(const f4*)(semb + (size_t)k * HW);

  // ---- prologue stage 1: actv[j] = bs[j] + lang[b,:] . Ws[j,:] ----
  #pragma unroll 8
  for (int m = 0; m < 32; ++m) {
    const int j = wave * 32 + m;
    const f4 wv = *(const f4*)(Ws + (size_t)j * LANG + lane * 4);
    float p = lv.x * wv.x + lv.y * wv.y + lv.z * wv.z + lv.w * wv.w;
    #pragma unroll
    for (int off = 32; off; off >>= 1) p += __shfl_xor(p, off);
    if (lane == 0) actv[j] = p + bs[j];
  }
  __syncthreads();

  // ---- prologue stage 2: 12 dots of length 128, 3 per wave ----
  const float a0 = actv[lane * 2], a1 = actv[lane * 2 + 1];
  #pragma unroll
  for (int r = 0; r < 3; ++r) {
    const int k = wave + 4 * r;              // 0..11
    const int kk = (k < NOP) ? k : k - NOP;  // row in Wg/Wb
    const float* W = ((k < NOP) ? Wg : Wb) + kk * NH;
    float p = a0 * W[lane * 2] + a1 * W[lane * 2 + 1];
    #pragma unroll
    for (int off = 32; off; off >>= 1) p += __shfl_xor(p, off);
    if (lane == 0) {
      const float bias = (k < NOP) ? bg[kk] : bb[kk];
      cf[k] = (p + bias) * Wr[kk];
    }
  }
  __syncthreads();

  // ---- combine (Wr/br are scalar-cached, uniform) ----
  float wrsum = 0.f;
  #pragma unroll
  for (int k = 0; k < NOP; ++k) wrsum += Wr[k];
  const float brv = br[0];
  f4 scale = {wrsum, wrsum, wrsum, wrsum};
  f4 shift = {brv, brv, brv, brv};
  #pragma unroll
  for (int k = 0; k < NOP; ++k) {
    scale += cf[k] * sv[k];
    shift += cf[NOP + k] * sv[k];
  }

  // ---- store 8 channels ----
  float* ob = out + base;
  #pragma unroll
  for (int c = 0; c < CCH; ++c)
    *(f4*)(ob + (size_t)c * HW) = xa[c] * scale + shift;
}

extern "C" void kernel_launch(void* const* d_in, const int* in_sizes, int n_in,
                              void* d_out, int out_size, void* d_ws, size_t ws_size,
                              hipStream_t stream) {
  const float* x    = (const float*)d_in[0];
  const float* lang = (const float*)d_in[1];
  const float* sem  = (const float*)d_in[2];
  const float* Ws   = (const float*)d_in[3];
  const float* bs   = (const float*)d_in[4];
  const float* Wg   = (const float*)d_in[5];
  const float* bg   = (const float*)d_in[6];
  const float* Wb   = (const float*)d_in[7];
  const float* bb   = (const float*)d_in[8];
  const float* Wr   = (const float*)d_in[9];
  const float* br   = (const float*)d_in[10];
  float* out = (float*)d_out;

  dim3 grid(HW / (256 * 4), NCH / CCH, 4);  // (16, 16, 4) = 1024 blocks
  fused_kernel<<<grid, dim3(256), 0, stream>>>(x, lang, sem, Ws, bs, Wg, bg,
                                               Wb, bb, Wr, br, out);
}